// Round 7
// baseline (577.665 us; speedup 1.0000x reference)
//
#include <hip/hip_runtime.h>
#include <hip/hip_bf16.h>
#include <math.h>

#define Bsz 4
#define Tsz 2048
#define Csz 1024
#define Hsz 16
#define Dsz 64
#define Msz (Bsz * Tsz)   // 8192 rows

typedef __attribute__((ext_vector_type(8))) __bf16 bf16x8;
typedef __attribute__((ext_vector_type(2))) __bf16 bf16x2;
typedef __attribute__((ext_vector_type(4))) float f32x4;

#define GLOBAL_AS __attribute__((address_space(1)))
#define LDS_AS    __attribute__((address_space(3)))

// ---------------- block-wide reductions (256 threads = 4 waves of 64) -------

__device__ __forceinline__ float block_sum256(float v, float* sh) {
#pragma unroll
    for (int o = 32; o > 0; o >>= 1) v += __shfl_down(v, o, 64);
    int lane = threadIdx.x & 63, w = threadIdx.x >> 6;
    __syncthreads();
    if (lane == 0) sh[w] = v;
    __syncthreads();
    return sh[0] + sh[1] + sh[2] + sh[3];
}

// ---------------- LayerNorm -> bf16; input fp32 (xf) or bf16 (xb) -----------

__global__ __launch_bounds__(256) void layernorm_bf16(const float* __restrict__ xf,
                                                      const __bf16* __restrict__ xb,
                                                      const float* __restrict__ g,
                                                      const float* __restrict__ b,
                                                      __bf16* __restrict__ out) {
    __shared__ float sh[4];
    const int row = blockIdx.x;
    float v[4];
    float s = 0.f, ss = 0.f;
    if (xf) {
        const float* xr = xf + (size_t)row * Csz;
#pragma unroll
        for (int i = 0; i < 4; i++) {
            v[i] = xr[threadIdx.x + i * 256];
            s += v[i];
            ss += v[i] * v[i];
        }
    } else {
        const __bf16* xr = xb + (size_t)row * Csz;
#pragma unroll
        for (int i = 0; i < 4; i++) {
            v[i] = (float)xr[threadIdx.x + i * 256];
            s += v[i];
            ss += v[i] * v[i];
        }
    }
    float tot = block_sum256(s, sh);
    float mean = tot * (1.0f / Csz);
    float tot2 = block_sum256(ss, sh);
    float var = tot2 * (1.0f / Csz) - mean * mean;
    float inv = rsqrtf(var + 1e-5f);
    __bf16* orow = out + (size_t)row * Csz;
#pragma unroll
    for (int i = 0; i < 4; i++) {
        int c = threadIdx.x + i * 256;
        orow[c] = (__bf16)((v[i] - mean) * inv * g[c] + b[c]);
    }
}

// ---------------- weight transpose + bf16 cast: W(KxN) f32 -> Wt(NxK) bf16 --

__global__ __launch_bounds__(256) void transpose_bf16(const float* __restrict__ W,
                                                      __bf16* __restrict__ Wt,
                                                      int K, int N) {
    __shared__ float t[32][33];
    const int k0 = blockIdx.y * 32, n0 = blockIdx.x * 32;
    const int c = threadIdx.x & 31, r8 = threadIdx.x >> 5;
#pragma unroll
    for (int it = 0; it < 4; it++) {
        int r = r8 + it * 8;
        t[r][c] = W[(size_t)(k0 + r) * N + n0 + c];
    }
    __syncthreads();
#pragma unroll
    for (int it = 0; it < 4; it++) {
        int r = r8 + it * 8;  // n-offset
        Wt[(size_t)(n0 + r) * K + k0 + c] = (__bf16)t[c][r];
    }
}

// batched version for the four 1024x1024 weights (one launch)
__global__ __launch_bounds__(256) void transpose4_bf16(const float* __restrict__ Wa,
                                                       const float* __restrict__ Wb,
                                                       const float* __restrict__ Wc,
                                                       const float* __restrict__ Wd,
                                                       __bf16* __restrict__ Ta,
                                                       __bf16* __restrict__ Tb,
                                                       __bf16* __restrict__ Tc,
                                                       __bf16* __restrict__ Td) {
    __shared__ float t[32][33];
    const float* W = (blockIdx.z == 0) ? Wa : (blockIdx.z == 1) ? Wb : (blockIdx.z == 2) ? Wc : Wd;
    __bf16* Wt = (blockIdx.z == 0) ? Ta : (blockIdx.z == 1) ? Tb : (blockIdx.z == 2) ? Tc : Td;
    const int k0 = blockIdx.y * 32, n0 = blockIdx.x * 32;
    const int c = threadIdx.x & 31, r8 = threadIdx.x >> 5;
#pragma unroll
    for (int it = 0; it < 4; it++) {
        int r = r8 + it * 8;
        t[r][c] = W[(size_t)(k0 + r) * Csz + n0 + c];
    }
    __syncthreads();
#pragma unroll
    for (int it = 0; it < 4; it++) {
        int r = r8 + it * 8;
        Wt[(size_t)(n0 + r) * Csz + k0 + c] = (__bf16)t[c][r];
    }
}

// ---------------- bf16 MFMA GEMM, BK=64, XOR-swizzled LDS, XCD supertiles ---
// C = A(M x *) @ B with B transposed: Bt(N x *), row stride ld (shared k-range
// offset handled by caller via pointer arithmetic). 128x128 tile, 4 waves.
// Block (x,y) remapped so XCD k (~= linear%8) owns y = k (mod 8) and all x:
// per-XCD working set = 8x8 supertile -> A and B panels L2-resident.
// Epilogue: +bias, relu, +residf (fp32) or +residb (bf16); writes Cf and/or Cb.

__global__ __launch_bounds__(256) void gemm_bf16(const __bf16* __restrict__ A,
                                                 const __bf16* __restrict__ Bt,
                                                 float* __restrict__ Cf,
                                                 __bf16* __restrict__ Cb,
                                                 int M, int N, int K, int ld,
                                                 const float* __restrict__ bias,
                                                 const float* __restrict__ residf,
                                                 const __bf16* __restrict__ residb,
                                                 int do_relu) {
    __shared__ __bf16 As[128 * 64];   // 16 KB
    __shared__ __bf16 Bs[128 * 64];   // 16 KB

    const int tid = threadIdx.x;
    const int lane = tid & 63;
    const int w = tid >> 6;

    // XCD supertile swizzle: lin%8 selects y-low (XCD), x cycles next.
    const int gx = gridDim.x;
    const int lin = blockIdx.x + gx * blockIdx.y;
    const int t8 = lin >> 3;
    const int bx = t8 % gx;
    const int by = (lin & 7) + 8 * (t8 / gx);

    const int rowBase = by * 128;
    const int colBase = bx * 128;
    const int wr = (w & 1) * 64;
    const int wc = (w >> 1) * 64;

    const int m16 = lane & 15;
    const int kg = lane >> 4;
    const int swz = m16 & 7;

    // staging: wave w covers rows w*32..+31 of both tiles, 8 rows per step
    const int sr = lane >> 3;     // row within 8-row group
    const int sc = lane & 7;      // LDS chunk slot
    const int gcs = sc ^ sr;      // fetched global chunk (swizzle key row&7)

    f32x4 acc[4][4] = {};

    for (int k0 = 0; k0 < K; k0 += 64) {
        __syncthreads();  // prior-iter LDS reads complete
#pragma unroll
        for (int it = 0; it < 4; it++) {
            int lr = w * 32 + it * 8;
            const __bf16* ga = A + (size_t)(rowBase + lr + sr) * ld + k0 + gcs * 8;
            __builtin_amdgcn_global_load_lds((const GLOBAL_AS unsigned int*)ga,
                                             (LDS_AS unsigned int*)(As + lr * 64),
                                             16, 0, 0);
            const __bf16* gb = Bt + (size_t)(colBase + lr + sr) * ld + k0 + gcs * 8;
            __builtin_amdgcn_global_load_lds((const GLOBAL_AS unsigned int*)gb,
                                             (LDS_AS unsigned int*)(Bs + lr * 64),
                                             16, 0, 0);
        }
        __syncthreads();  // drains vmcnt -> tiles visible

#pragma unroll
        for (int s = 0; s < 2; s++) {
            const int slot = ((s * 4 + kg) ^ swz) * 8;
            bf16x8 af[4], bfv[4];
#pragma unroll
            for (int i = 0; i < 4; i++)
                af[i] = *(const bf16x8*)(As + (wr + i * 16 + m16) * 64 + slot);
#pragma unroll
            for (int j = 0; j < 4; j++)
                bfv[j] = *(const bf16x8*)(Bs + (wc + j * 16 + m16) * 64 + slot);
#pragma unroll
            for (int i = 0; i < 4; i++)
#pragma unroll
                for (int j = 0; j < 4; j++)
                    acc[i][j] = __builtin_amdgcn_mfma_f32_16x16x32_bf16(af[i], bfv[j], acc[i][j], 0, 0, 0);
        }
    }

    // epilogue: C/D layout col=lane&15, row=(lane>>4)*4+reg
    const int cn = lane & 15;
    const int rq = (lane >> 4) * 4;
    float bj[4];
#pragma unroll
    for (int j = 0; j < 4; j++)
        bj[j] = bias ? bias[colBase + wc + j * 16 + cn] : 0.f;

#pragma unroll
    for (int i = 0; i < 4; i++) {
#pragma unroll
        for (int r = 0; r < 4; r++) {
            int m = rowBase + wr + i * 16 + rq + r;
            size_t rowOff = (size_t)m * N;
#pragma unroll
            for (int j = 0; j < 4; j++) {
                int n = colBase + wc + j * 16 + cn;
                float v = acc[i][j][r] + bj[j];
                if (do_relu) v = fmaxf(v, 0.f);
                if (residf) v += residf[rowOff + n];
                if (residb) v += (float)residb[rowOff + n];
                if (Cf) Cf[rowOff + n] = v;
                if (Cb) Cb[rowOff + n] = (__bf16)v;
            }
        }
    }
}

// ---------------- MFMA flash attention, static-shift softmax ----------------

__global__ __launch_bounds__(256, 4) void attn_mfma(const __bf16* __restrict__ QKV,
                                                    __bf16* __restrict__ O) {
    __shared__ __bf16 Ks[64 * 64];    // swizzled chunk layout, 8 KB
    __shared__ __bf16 Vt[64 * 72];    // Vt[d][key], padded, 9 KB
    __shared__ __bf16 Ps[128 * 72];   // P[q][key], padded, 18 KB -> 35 KB total

    const int tid = threadIdx.x;
    const int lane = tid & 63;
    const int w = tid >> 6;
    const int bh = blockIdx.x;            // 0..63
    const int b = bh >> 4, h = bh & 15;
    const int qt = (int)gridDim.y - 1 - (int)blockIdx.y;  // heavy tiles first
    const int qbase = qt * 128;
    const int ld3C = 3 * Csz;

    const __bf16* Qg = QKV + (size_t)(b * Tsz) * ld3C + h * Dsz;
    const __bf16* Kg = Qg + Csz;
    const __bf16* Vg = Qg + 2 * Csz;

    const int m16 = lane & 15;
    const int kg = lane >> 4;
    const int rq = kg * 4;
    const int wrow = w * 32;
    const int swz = m16 & 7;

    // Q fragments in registers
    bf16x8 aq[2][2];
#pragma unroll
    for (int i = 0; i < 2; i++)
#pragma unroll
        for (int s = 0; s < 2; s++)
            aq[i][s] = *(const bf16x8*)(Qg + (size_t)(qbase + wrow + i * 16 + m16) * ld3C + (s * 4 + kg) * 8);

    const int sr = lane >> 3;
    const int sc = lane & 7;
    const int gcs = sc ^ sr;

    const int kp = (lane & 31) * 2;
    const int dg = w * 2 + (lane >> 5);

    f32x4 Oacc[2][4];
    float l_part[2][4];
#pragma unroll
    for (int i = 0; i < 2; i++)
#pragma unroll
        for (int j = 0; j < 4; j++) Oacc[i][j] = (f32x4){0.f, 0.f, 0.f, 0.f};
#pragma unroll
    for (int i = 0; i < 2; i++)
#pragma unroll
        for (int r = 0; r < 4; r++) l_part[i][r] = 0.f;

    const float CEXP = 0.18033688f;  // 0.125 * log2(e)

    const int nkt = 2 * qt + 2;
    for (int kt = 0; kt < nkt; kt++) {
        const int kbase = kt * 64;
        __syncthreads();

#pragma unroll
        for (int it = 0; it < 2; it++) {
            int lr = w * 16 + it * 8 + sr;
            const __bf16* src = Kg + (size_t)(kbase + lr) * ld3C + gcs * 8;
            __builtin_amdgcn_global_load_lds((const GLOBAL_AS unsigned int*)src,
                                             (LDS_AS unsigned int*)(Ks + (w * 16 + it * 8) * 64),
                                             16, 0, 0);
        }
        bf16x8 v0 = *(const bf16x8*)(Vg + (size_t)(kbase + kp) * ld3C + dg * 8);
        bf16x8 v1 = *(const bf16x8*)(Vg + (size_t)(kbase + kp + 1) * ld3C + dg * 8);
        __syncthreads();

        f32x4 S[2][4];
#pragma unroll
        for (int i = 0; i < 2; i++)
#pragma unroll
            for (int j = 0; j < 4; j++) S[i][j] = (f32x4){0.f, 0.f, 0.f, 0.f};
#pragma unroll
        for (int s = 0; s < 2; s++) {
            bf16x8 bk[4];
#pragma unroll
            for (int j = 0; j < 4; j++)
                bk[j] = *(const bf16x8*)(Ks + (j * 16 + m16) * 64 + (((s * 4 + kg) ^ swz) * 8));
#pragma unroll
            for (int i = 0; i < 2; i++)
#pragma unroll
                for (int j = 0; j < 4; j++)
                    S[i][j] = __builtin_amdgcn_mfma_f32_16x16x32_bf16(aq[i][s], bk[j], S[i][j], 0, 0, 0);
        }

        const bool domask = (kt >= 2 * qt);
#pragma unroll
        for (int i = 0; i < 2; i++) {
#pragma unroll
            for (int j = 0; j < 4; j++) {
#pragma unroll
                for (int r = 0; r < 4; r++) {
                    float arg = S[i][j][r] * CEXP;
                    if (domask && (kbase + j * 16 + m16 > qbase + wrow + i * 16 + rq + r))
                        arg = -INFINITY;
                    float e = exp2f(arg);
                    S[i][j][r] = e;
                    l_part[i][r] += e;
                }
            }
        }

#pragma unroll
        for (int i = 0; i < 2; i++)
#pragma unroll
            for (int j = 0; j < 4; j++)
#pragma unroll
                for (int r = 0; r < 4; r++)
                    Ps[(wrow + i * 16 + rq + r) * 72 + j * 16 + m16] = (__bf16)S[i][j][r];
#pragma unroll
        for (int e = 0; e < 8; e++) {
            bf16x2 pr;
            pr[0] = v0[e];
            pr[1] = v1[e];
            *(bf16x2*)(Vt + (dg * 8 + e) * 72 + kp) = pr;
        }
        __syncthreads();

#pragma unroll
        for (int s = 0; s < 2; s++) {
            bf16x8 ap[2], bv[4];
#pragma unroll
            for (int i = 0; i < 2; i++)
                ap[i] = *(const bf16x8*)(Ps + (wrow + i * 16 + m16) * 72 + s * 32 + kg * 8);
#pragma unroll
            for (int j = 0; j < 4; j++)
                bv[j] = *(const bf16x8*)(Vt + (j * 16 + m16) * 72 + s * 32 + kg * 8);
#pragma unroll
            for (int i = 0; i < 2; i++)
#pragma unroll
                for (int j = 0; j < 4; j++)
                    Oacc[i][j] = __builtin_amdgcn_mfma_f32_16x16x32_bf16(ap[i], bv[j], Oacc[i][j], 0, 0, 0);
        }
    }

#pragma unroll
    for (int i = 0; i < 2; i++) {
#pragma unroll
        for (int r = 0; r < 4; r++) {
            float l = l_part[i][r];
#pragma unroll
            for (int msk = 1; msk < 16; msk <<= 1) l += __shfl_xor(l, msk, 64);
            const float inv = 1.0f / l;
            const int qrow = qbase + wrow + i * 16 + rq + r;
            __bf16* orow = O + (size_t)(b * Tsz + qrow) * Csz + h * Dsz;
#pragma unroll
            for (int j = 0; j < 4; j++)
                orow[j * 16 + m16] = (__bf16)(Oacc[i][j][r] * inv);
        }
    }
}

// ---------------- launch ----------------------------------------------------

extern "C" void kernel_launch(void* const* d_in, const int* in_sizes, int n_in,
                              void* d_out, int out_size, void* d_ws, size_t ws_size,
                              hipStream_t stream) {
    const float* x     = (const float*)d_in[0];
    const float* Wq    = (const float*)d_in[1];
    const float* Wk    = (const float*)d_in[2];
    const float* Wv    = (const float*)d_in[3];
    const float* Wo    = (const float*)d_in[4];
    const float* bo    = (const float*)d_in[5];
    const float* ln1_g = (const float*)d_in[6];
    const float* ln1_b = (const float*)d_in[7];
    const float* ln2_g = (const float*)d_in[8];
    const float* ln2_b = (const float*)d_in[9];
    const float* W1    = (const float*)d_in[10];
    const float* b1    = (const float*)d_in[11];
    const float* W2    = (const float*)d_in[12];
    const float* b2    = (const float*)d_in[13];
    float* out = (float*)d_out;

    const size_t MB = 1u << 20;
    char* w = (char*)d_ws;
    __bf16* h    = (__bf16*)(w + 0);         // 16 MB
    __bf16* Wqkv = (__bf16*)(w + 16 * MB);   // 6 MB
    __bf16* Wot  = (__bf16*)(w + 22 * MB);   // 2 MB
    __bf16* W1t  = (__bf16*)(w + 24 * MB);   // 8 MB
    __bf16* W2t  = (__bf16*)(w + 32 * MB);   // 8 MB
    __bf16* QKVb = (__bf16*)(w + 40 * MB);   // 48 MB (dead after attn)
    __bf16* AO   = (__bf16*)(w + 88 * MB);   // 16 MB (dead after proj)
    __bf16* ff1  = (__bf16*)(w + 40 * MB);   // 64 MB, overlays QKVb+AO
    __bf16* x2b  = (__bf16*)(w + 104 * MB);  // 16 MB (bf16 residual x2)
    // high-water: 120 MB

    // weight transposes (f32 KxN -> bf16 NxK)
    transpose4_bf16<<<dim3(32, 32, 4), 256, 0, stream>>>(Wq, Wk, Wv, Wo,
                                                         Wqkv, Wqkv + 1024 * 1024, Wqkv + 2048 * 1024, Wot);
    transpose_bf16<<<dim3(4 * Csz / 32, Csz / 32), 256, 0, stream>>>(W1, W1t, Csz, 4 * Csz);
    transpose_bf16<<<dim3(Csz / 32, 4 * Csz / 32), 256, 0, stream>>>(W2, W2t, 4 * Csz, Csz);

    // --- attention branch ---
    layernorm_bf16<<<Msz, 256, 0, stream>>>(x, nullptr, ln1_g, ln1_b, h);
    gemm_bf16<<<dim3(3 * Csz / 128, Msz / 128), 256, 0, stream>>>(
        h, Wqkv, nullptr, QKVb, Msz, 3 * Csz, Csz, Csz, nullptr, nullptr, nullptr, 0);
    attn_mfma<<<dim3(Bsz * Hsz, Tsz / 128), 256, 0, stream>>>(QKVb, AO);
    // x2 = x + AO @ Wo + bo -> bf16 x2b
    gemm_bf16<<<dim3(Csz / 128, Msz / 128), 256, 0, stream>>>(
        AO, Wot, nullptr, x2b, Msz, Csz, Csz, Csz, bo, x, nullptr, 0);

    // --- FFN branch ---
    layernorm_bf16<<<Msz, 256, 0, stream>>>(nullptr, x2b, ln2_g, ln2_b, h);
    gemm_bf16<<<dim3(4 * Csz / 128, Msz / 128), 256, 0, stream>>>(
        h, W1t, nullptr, ff1, Msz, 4 * Csz, Csz, Csz, b1, nullptr, nullptr, 1);
    // FFN2 as two sequential in-place half-K GEMMs:
    //   out = x2b + ff1[:, :2048] @ W2t[:, :2048]^T
    gemm_bf16<<<dim3(Csz / 128, Msz / 128), 256, 0, stream>>>(
        ff1, W2t, out, nullptr, Msz, Csz, 2 * Csz, 4 * Csz, nullptr, nullptr, x2b, 0);
    //   out += ff1[:, 2048:] @ W2t[:, 2048:]^T + b2
    gemm_bf16<<<dim3(Csz / 128, Msz / 128), 256, 0, stream>>>(
        ff1 + 2 * Csz, W2t + 2 * Csz, out, nullptr, Msz, Csz, 2 * Csz, 4 * Csz, b2, out, nullptr, 0);
}